// Round 1
// baseline (1480.801 us; speedup 1.0000x reference)
//
#include <hip/hip_runtime.h>
#include <hip/hip_bf16.h>

// LGCN_Encoder: ego=[N,64] fp32, v=[N,512] fp32, filters=[3,512] fp32
// per layer: proj = V^T @ ego  [512,64];  ego = V @ (f_k * proj)  [N,64]
// out = (ego0+ego1+ego2+ego3)/4, flat [N,64] (users then items = contiguous).

#define N_USERS 29858
#define N_ITEMS 40981
#define N_TOTAL 70839
#define D 64
#define F 512
#define N_LAYERS 3

// ---------------------------------------------------------------- init
// ego = concat(user, item); out = ego  (both fully overwritten; flat copy)
__global__ __launch_bounds__(256) void init_kernel(
    const float4* __restrict__ u, const float4* __restrict__ it,
    float4* __restrict__ ego, float4* __restrict__ out) {
  const int nu4 = N_USERS * D / 4;
  const int nt4 = N_TOTAL * D / 4;
  int i = blockIdx.x * blockDim.x + threadIdx.x;
  if (i < nt4) {
    float4 val = (i < nu4) ? u[i] : it[i - nu4];
    ego[i] = val;
    out[i] = val;
  }
}

// ---------------------------------------------------------------- reduce
// proj[f][d] += sum_n v[n][f] * ego[n][d]   (atomic across n-chunks)
// grid: (4 f-slices of 128) x (n-chunks of 256 rows). block=256.
#define RED_TN 32
#define RED_ITERS 8
#define RED_ROWS (RED_TN * RED_ITERS)  // 256 rows per chunk

__global__ __launch_bounds__(256) void reduce_kernel(
    const float* __restrict__ v, const float* __restrict__ ego,
    float* __restrict__ proj) {
  __shared__ float Vt[RED_TN][128];
  __shared__ float Et[RED_TN][64];

  const int fbase = blockIdx.x * 128;
  const int n0 = blockIdx.y * RED_ROWS;
  const int t = threadIdx.x;
  const int td = t & 15;   // d-group: d0 = td*4
  const int tf = t >> 4;   // f-group: f0 = tf*8

  float acc[8][4] = {};

  for (int itr = 0; itr < RED_ITERS; ++itr) {
    const int nb = n0 + itr * RED_TN;
    // stage V tile: 32 rows x 128 floats (1024 float4, 4/thread)
#pragma unroll
    for (int l = 0; l < 4; ++l) {
      int idx = t + l * 256;
      int r = idx >> 5, c4 = idx & 31;
      int n = nb + r;
      float4 val = (n < N_TOTAL)
          ? *(const float4*)(v + (size_t)n * F + fbase + c4 * 4)
          : float4{0.f, 0.f, 0.f, 0.f};
      *(float4*)(&Vt[r][c4 * 4]) = val;
    }
    // stage ego tile: 32 rows x 64 floats (512 float4, 2/thread)
#pragma unroll
    for (int l = 0; l < 2; ++l) {
      int idx = t + l * 256;
      int r = idx >> 4, c4 = idx & 15;
      int n = nb + r;
      float4 val = (n < N_TOTAL)
          ? *(const float4*)(ego + (size_t)n * D + c4 * 4)
          : float4{0.f, 0.f, 0.f, 0.f};
      *(float4*)(&Et[r][c4 * 4]) = val;
    }
    __syncthreads();

#pragma unroll
    for (int r = 0; r < RED_TN; ++r) {
      float4 e = *(float4*)(&Et[r][td * 4]);
      float4 va = *(float4*)(&Vt[r][tf * 8]);
      float4 vb = *(float4*)(&Vt[r][tf * 8 + 4]);
      float vv[8] = {va.x, va.y, va.z, va.w, vb.x, vb.y, vb.z, vb.w};
      float ee[4] = {e.x, e.y, e.z, e.w};
#pragma unroll
      for (int i = 0; i < 8; ++i)
#pragma unroll
        for (int j = 0; j < 4; ++j) acc[i][j] += vv[i] * ee[j];
    }
    __syncthreads();
  }

#pragma unroll
  for (int i = 0; i < 8; ++i) {
    int f = fbase + tf * 8 + i;
#pragma unroll
    for (int j = 0; j < 4; ++j)
      atomicAdd(&proj[f * D + td * 4 + j], acc[i][j]);
  }
}

// ---------------------------------------------------------------- expand
// ego_new[n][d] = sum_f v[n][f] * fk[f] * proj[f][d]
// out[n][d] = (out[n][d] + ego_new[n][d]) * scale
// block=256, 128 rows/block, thread tile 8 rows x 4 d, f-sliced by 64.
#define EXP_RB 128
#define EXP_FS 64

__global__ __launch_bounds__(256) void expand_kernel(
    const float* __restrict__ v, const float* __restrict__ proj,
    const float* __restrict__ filt, float* __restrict__ out,
    float* __restrict__ ego_out, float scale, int write_ego) {
  __shared__ float Vs[EXP_RB][EXP_FS + 1];  // +1 pad: 2-way banks only
  __shared__ float Ws[EXP_FS][D];

  const int n0 = blockIdx.x * EXP_RB;
  const int t = threadIdx.x;
  const int dg = t & 15;   // d0 = dg*4
  const int rg = t >> 4;   // rows rg*8 .. rg*8+7

  float acc[8][4] = {};

  for (int fs = 0; fs < F; fs += EXP_FS) {
    // stage V: 128 rows x 64 floats (2048 float4, 8/thread)
#pragma unroll
    for (int l = 0; l < 8; ++l) {
      int idx = t + l * 256;
      int r = idx >> 4, c4 = idx & 15;
      int n = n0 + r;
      float4 val = (n < N_TOTAL)
          ? *(const float4*)(v + (size_t)n * F + fs + c4 * 4)
          : float4{0.f, 0.f, 0.f, 0.f};
      *(float4*)(&Vs[r][c4 * 4]) = val;
    }
    // stage W = fk * proj slice: 64 f x 64 d (1024 float4, 4/thread)
#pragma unroll
    for (int l = 0; l < 4; ++l) {
      int idx = t + l * 256;
      int f = idx >> 4, c4 = idx & 15;
      float fk = filt[fs + f];
      float4 p = *(const float4*)(proj + (size_t)(fs + f) * D + c4 * 4);
      float4 w = {p.x * fk, p.y * fk, p.z * fk, p.w * fk};
      *(float4*)(&Ws[f][c4 * 4]) = w;
    }
    __syncthreads();

#pragma unroll
    for (int f4 = 0; f4 < EXP_FS; f4 += 4) {
      float4 wv[4];
#pragma unroll
      for (int j = 0; j < 4; ++j) wv[j] = *(float4*)(&Ws[f4 + j][dg * 4]);
#pragma unroll
      for (int i = 0; i < 8; ++i) {
        float4 vv = *(float4*)(&Vs[rg * 8 + i][f4]);
        acc[i][0] += vv.x * wv[0].x + vv.y * wv[1].x + vv.z * wv[2].x + vv.w * wv[3].x;
        acc[i][1] += vv.x * wv[0].y + vv.y * wv[1].y + vv.z * wv[2].y + vv.w * wv[3].y;
        acc[i][2] += vv.x * wv[0].z + vv.y * wv[1].z + vv.z * wv[2].z + vv.w * wv[3].z;
        acc[i][3] += vv.x * wv[0].w + vv.y * wv[1].w + vv.z * wv[2].w + vv.w * wv[3].w;
      }
    }
    __syncthreads();
  }

#pragma unroll
  for (int i = 0; i < 8; ++i) {
    int n = n0 + rg * 8 + i;
    if (n < N_TOTAL) {
      float4* op = (float4*)(out + (size_t)n * D + dg * 4);
      float4 o = *op;
      float4 e = {acc[i][0], acc[i][1], acc[i][2], acc[i][3]};
      o.x = (o.x + e.x) * scale;
      o.y = (o.y + e.y) * scale;
      o.z = (o.z + e.z) * scale;
      o.w = (o.w + e.w) * scale;
      *op = o;
      if (write_ego)
        *(float4*)(ego_out + (size_t)n * D + dg * 4) = e;
    }
  }
}

// ---------------------------------------------------------------- launch
extern "C" void kernel_launch(void* const* d_in, const int* in_sizes, int n_in,
                              void* d_out, int out_size, void* d_ws, size_t ws_size,
                              hipStream_t stream) {
  const float* user_emb = (const float*)d_in[0];
  const float* item_emb = (const float*)d_in[1];
  const float* v        = (const float*)d_in[2];
  const float* filters  = (const float*)d_in[3];
  float* out = (float*)d_out;

  // workspace: ego [N*D] + proj [F*D]  (expand never reads old ego, so one buffer)
  float* ego  = (float*)d_ws;
  float* proj = ego + (size_t)N_TOTAL * D;

  // init: ego = concat(user,item); out = ego
  {
    int nt4 = N_TOTAL * D / 4;
    int blocks = (nt4 + 255) / 256;
    init_kernel<<<blocks, 256, 0, stream>>>(
        (const float4*)user_emb, (const float4*)item_emb,
        (float4*)ego, (float4*)out);
  }

  const int n_chunks = (N_TOTAL + RED_ROWS - 1) / RED_ROWS;   // 277
  const int exp_blocks = (N_TOTAL + EXP_RB - 1) / EXP_RB;     // 554

  for (int k = 0; k < N_LAYERS; ++k) {
    hipMemsetAsync(proj, 0, (size_t)F * D * sizeof(float), stream);
    reduce_kernel<<<dim3(4, n_chunks), 256, 0, stream>>>(v, ego, proj);
    float scale = (k == N_LAYERS - 1) ? (1.0f / (N_LAYERS + 1)) : 1.0f;
    int write_ego = (k < N_LAYERS - 1) ? 1 : 0;
    expand_kernel<<<exp_blocks, 256, 0, stream>>>(
        v, proj, filters + (size_t)k * F, out, ego, scale, write_ego);
  }
}

// Round 2
// 762.447 us; speedup vs baseline: 1.9422x; 1.9422x over previous
//
#include <hip/hip_runtime.h>
#include <hip/hip_bf16.h>

// LGCN_Encoder, bf16-split MFMA version.
// per layer: proj = V^T @ ego ; ego = V @ (diag(f_k) proj) ; out += ego ; /4 at end.
// fp32 operands split into bf16 hi/lo; product = ah*bh + ah*bl + al*bh (lo*lo dropped,
// ~2^-16 relative error, below fp32 accumulation noise at K=70839).
// MFMA 16x16x32_bf16: A[m=lane&15][k=(lane>>4)*8+j]; B[k][n=lane&15] same k-map;
// C/D: col=lane&15, row=(lane>>4)*4+reg   [HW-verified layouts, learn_hip m89/m91].

#define N_USERS 29858
#define N_TOTAL 70839
#define DQ 64
#define FD 512
#define N_LAYERS 3
#define NPAD 71168   // 139*512 >= N_TOTAL, multiple of 64; egoT row length
#define NKP 72       // LDS row pad (bf16 elems): 144B rows -> 16B aligned, uniform banks

typedef __attribute__((ext_vector_type(8))) short short8;
typedef __attribute__((ext_vector_type(4))) short short4v;
typedef __attribute__((ext_vector_type(4))) float f32x4;

__device__ __forceinline__ unsigned short bf16_rne(float x) {
  union { float f; unsigned u; } a; a.f = x;
  return (unsigned short)((a.u + 0x7FFFu + ((a.u >> 16) & 1u)) >> 16);
}
__device__ __forceinline__ float bf16_f(unsigned short h) {
  union { unsigned u; float f; } a; a.u = ((unsigned)h) << 16;
  return a.f;
}
__device__ __forceinline__ void split2(float x, unsigned short& h, unsigned short& l) {
  h = bf16_rne(x);
  l = bf16_rne(x - bf16_f(h));
}

// ---------------------------------------------------------------- init
// out = concat(user,item); egoT_h/l[d][n] = split(ego[n][d]); zero-fill n in [N_TOTAL,NPAD)
__global__ __launch_bounds__(256) void init_kernel(
    const float* __restrict__ u, const float* __restrict__ it,
    float* __restrict__ out, unsigned short* __restrict__ egoT_h,
    unsigned short* __restrict__ egoT_l) {
  const int n0 = blockIdx.x * 64;
  const int t = threadIdx.x;
  const int nq = t & 15, dq = t >> 4;  // thread owns 4 n x 4 d
  f32x4 rows[4];
#pragma unroll
  for (int r = 0; r < 4; ++r) {
    int n = n0 + nq * 4 + r;
    f32x4 val = {0.f, 0.f, 0.f, 0.f};
    if (n < N_TOTAL) {
      const float* src = (n < N_USERS) ? (u + (size_t)n * DQ)
                                       : (it + (size_t)(n - N_USERS) * DQ);
      val = *(const f32x4*)(src + dq * 4);
      *(f32x4*)(out + (size_t)n * DQ + dq * 4) = val;
    }
    rows[r] = val;
  }
#pragma unroll
  for (int i = 0; i < 4; ++i) {
    int d = dq * 4 + i;
    short4v hv, lv;
#pragma unroll
    for (int r = 0; r < 4; ++r) {
      unsigned short h, l;
      split2(rows[r][i], h, l);
      hv[r] = (short)h; lv[r] = (short)l;
    }
    *(short4v*)(egoT_h + (size_t)d * NPAD + n0 + nq * 4) = hv;
    *(short4v*)(egoT_l + (size_t)d * NPAD + n0 + nq * 4) = lv;
  }
}

// ---------------------------------------------------------------- reduce
// proj[f][d] += V^T ego over this block's n-range. A = V^T via LDS transpose,
// B = egoT (pre-split bf16) direct from global. f-slice 64/block, 512 n/block.
#define RED_CI 8
__global__ __launch_bounds__(256, 4) void reduce_kernel(
    const float* __restrict__ v, const unsigned short* __restrict__ egoT_h,
    const unsigned short* __restrict__ egoT_l, float* __restrict__ proj) {
  __shared__ unsigned short VT_h[64 * NKP];
  __shared__ unsigned short VT_l[64 * NKP];
  const int fb = blockIdx.x * 64;
  const int nbase = blockIdx.y * (RED_CI * 64);
  const int t = threadIdx.x;
  const int nq = t & 15, fq = t >> 4;       // staging roles: 4n x 4f per thread
  const int lane = t & 63, wv = t >> 6;
  const int m16 = lane & 15, quad = lane >> 4;

  f32x4 acc[4];
#pragma unroll
  for (int i = 0; i < 4; ++i) acc[i] = (f32x4){0.f, 0.f, 0.f, 0.f};

  // prologue load for iter 0
  f32x4 rows[4];
#pragma unroll
  for (int r = 0; r < 4; ++r) {
    int n = nbase + nq * 4 + r;
    rows[r] = (n < N_TOTAL) ? *(const f32x4*)(v + (size_t)n * FD + fb + fq * 4)
                            : (f32x4){0.f, 0.f, 0.f, 0.f};
  }

#pragma unroll 1
  for (int itr = 0; itr < RED_CI; ++itr) {
    const int n0 = nbase + itr * 64;
    __syncthreads();  // protect VT from previous iteration's readers
#pragma unroll
    for (int i = 0; i < 4; ++i) {
      int f = fq * 4 + i;
      short4v hv, lv;
#pragma unroll
      for (int r = 0; r < 4; ++r) {
        unsigned short h, l;
        split2(rows[r][i], h, l);
        hv[r] = (short)h; lv[r] = (short)l;
      }
      *(short4v*)(VT_h + f * NKP + nq * 4) = hv;
      *(short4v*)(VT_l + f * NKP + nq * 4) = lv;
    }
    // prefetch next iteration's V rows (overlaps MFMA + B loads below)
    if (itr + 1 < RED_CI) {
#pragma unroll
      for (int r = 0; r < 4; ++r) {
        int n = n0 + 64 + nq * 4 + r;
        rows[r] = (n < N_TOTAL) ? *(const f32x4*)(v + (size_t)n * FD + fb + fq * 4)
                                : (f32x4){0.f, 0.f, 0.f, 0.f};
      }
    }
    __syncthreads();
#pragma unroll
    for (int k0 = 0; k0 < 64; k0 += 32) {
      short8 ah = *(const short8*)(VT_h + (wv * 16 + m16) * NKP + k0 + quad * 8);
      short8 al = *(const short8*)(VT_l + (wv * 16 + m16) * NKP + k0 + quad * 8);
      int nk = n0 + k0 + quad * 8;
#pragma unroll
      for (int dt = 0; dt < 4; ++dt) {
        short8 bh = *(const short8*)(egoT_h + (size_t)(dt * 16 + m16) * NPAD + nk);
        short8 bl = *(const short8*)(egoT_l + (size_t)(dt * 16 + m16) * NPAD + nk);
        acc[dt] = __builtin_amdgcn_mfma_f32_16x16x32_bf16(ah, bh, acc[dt], 0, 0, 0);
        acc[dt] = __builtin_amdgcn_mfma_f32_16x16x32_bf16(ah, bl, acc[dt], 0, 0, 0);
        acc[dt] = __builtin_amdgcn_mfma_f32_16x16x32_bf16(al, bh, acc[dt], 0, 0, 0);
      }
    }
  }
  // C: row(f within 16) = quad*4+reg, col(d) = m16
#pragma unroll
  for (int dt = 0; dt < 4; ++dt)
#pragma unroll
    for (int reg = 0; reg < 4; ++reg)
      atomicAdd(&proj[(fb + wv * 16 + quad * 4 + reg) * DQ + dt * 16 + m16],
                acc[dt][reg]);
}

// ---------------------------------------------------------------- prep_w
// Wt[d][f] = split(filt[f] * proj[f][d])  (bf16 hi/lo, [64][512])
__global__ __launch_bounds__(256) void prep_w(
    const float* __restrict__ proj, const float* __restrict__ filt,
    unsigned short* __restrict__ wt_h, unsigned short* __restrict__ wt_l) {
  int idx = blockIdx.x * 256 + threadIdx.x;  // 8192 threads, 4 f each
  int d = idx >> 7;
  int f4 = (idx & 127) * 4;
  short4v hv, lv;
#pragma unroll
  for (int i = 0; i < 4; ++i) {
    int f = f4 + i;
    float w = filt[f] * proj[f * DQ + d];
    unsigned short h, l;
    split2(w, h, l);
    hv[i] = (short)h; lv[i] = (short)l;
  }
  *(short4v*)(wt_h + d * FD + f4) = hv;
  *(short4v*)(wt_l + d * FD + f4) = lv;
}

// ---------------------------------------------------------------- expand
// ego_new = V @ W; out = (out + ego_new)*scale; egoT_h/l updated (layers 0,1).
// No LDS: A frags are 32B-contiguous per lane from V (fp32, split in-reg);
// B frags 16B-contiguous from Wt (L2-resident 128KB).
__global__ __launch_bounds__(256, 3) void expand_kernel(
    const float* __restrict__ v, const unsigned short* __restrict__ wt_h,
    const unsigned short* __restrict__ wt_l, float* __restrict__ out,
    unsigned short* __restrict__ egoT_h, unsigned short* __restrict__ egoT_l,
    float scale, int write_ego) {
  const int t = threadIdx.x;
  const int lane = t & 63, wv = t >> 6;
  const int m16 = lane & 15, quad = lane >> 4;
  const int nb = blockIdx.x * 128 + wv * 32;  // wave's 32 rows
  int r0c = min(nb + m16, N_TOTAL - 1);
  int r1c = min(nb + 16 + m16, N_TOTAL - 1);
  const float* p0 = v + (size_t)r0c * FD + quad * 8;
  const float* p1 = v + (size_t)r1c * FD + quad * 8;

  f32x4 acc[2][4];
#pragma unroll
  for (int mt = 0; mt < 2; ++mt)
#pragma unroll
    for (int dt = 0; dt < 4; ++dt) acc[mt][dt] = (f32x4){0.f, 0.f, 0.f, 0.f};

#pragma unroll 2
  for (int k0 = 0; k0 < FD; k0 += 32) {
    f32x4 a0a = *(const f32x4*)(p0 + k0);
    f32x4 a0b = *(const f32x4*)(p0 + k0 + 4);
    f32x4 a1a = *(const f32x4*)(p1 + k0);
    f32x4 a1b = *(const f32x4*)(p1 + k0 + 4);
    short8 ah[2], al[2];
#pragma unroll
    for (int j = 0; j < 4; ++j) {
      unsigned short h, l;
      split2(a0a[j], h, l); ah[0][j] = (short)h; al[0][j] = (short)l;
      split2(a0b[j], h, l); ah[0][j + 4] = (short)h; al[0][j + 4] = (short)l;
      split2(a1a[j], h, l); ah[1][j] = (short)h; al[1][j] = (short)l;
      split2(a1b[j], h, l); ah[1][j + 4] = (short)h; al[1][j + 4] = (short)l;
    }
    int koff = k0 + quad * 8;
#pragma unroll
    for (int dt = 0; dt < 4; ++dt) {
      short8 bh = *(const short8*)(wt_h + (dt * 16 + m16) * FD + koff);
      short8 bl = *(const short8*)(wt_l + (dt * 16 + m16) * FD + koff);
      acc[0][dt] = __builtin_amdgcn_mfma_f32_16x16x32_bf16(ah[0], bh, acc[0][dt], 0, 0, 0);
      acc[0][dt] = __builtin_amdgcn_mfma_f32_16x16x32_bf16(ah[0], bl, acc[0][dt], 0, 0, 0);
      acc[0][dt] = __builtin_amdgcn_mfma_f32_16x16x32_bf16(al[0], bh, acc[0][dt], 0, 0, 0);
      acc[1][dt] = __builtin_amdgcn_mfma_f32_16x16x32_bf16(ah[1], bh, acc[1][dt], 0, 0, 0);
      acc[1][dt] = __builtin_amdgcn_mfma_f32_16x16x32_bf16(ah[1], bl, acc[1][dt], 0, 0, 0);
      acc[1][dt] = __builtin_amdgcn_mfma_f32_16x16x32_bf16(al[1], bh, acc[1][dt], 0, 0, 0);
    }
  }

  // epilogue: C row(n) = quad*4+reg (+mt*16), col(d) = m16 (+dt*16)
#pragma unroll
  for (int mt = 0; mt < 2; ++mt) {
    int nrow = nb + mt * 16 + quad * 4;
#pragma unroll
    for (int dt = 0; dt < 4; ++dt) {
      int d = dt * 16 + m16;
#pragma unroll
      for (int reg = 0; reg < 4; ++reg) {
        int n = nrow + reg;
        if (n < N_TOTAL) {
          float* op = out + (size_t)n * DQ + d;
          *op = (*op + acc[mt][dt][reg]) * scale;
        }
      }
      if (write_ego) {
        short4v hv, lv;
#pragma unroll
        for (int reg = 0; reg < 4; ++reg) {
          unsigned short h = 0, l = 0;
          if (nrow + reg < N_TOTAL) split2(acc[mt][dt][reg], h, l);
          hv[reg] = (short)h; lv[reg] = (short)l;
        }
        *(short4v*)(egoT_h + (size_t)d * NPAD + nrow) = hv;
        *(short4v*)(egoT_l + (size_t)d * NPAD + nrow) = lv;
      }
    }
  }
}

// ---------------------------------------------------------------- launch
extern "C" void kernel_launch(void* const* d_in, const int* in_sizes, int n_in,
                              void* d_out, int out_size, void* d_ws, size_t ws_size,
                              hipStream_t stream) {
  const float* user_emb = (const float*)d_in[0];
  const float* item_emb = (const float*)d_in[1];
  const float* v        = (const float*)d_in[2];
  const float* filters  = (const float*)d_in[3];
  float* out = (float*)d_out;

  // workspace layout
  unsigned short* egoT_h = (unsigned short*)d_ws;                       // 64*NPAD
  unsigned short* egoT_l = egoT_h + (size_t)DQ * NPAD;                  // 64*NPAD
  float* proj            = (float*)(egoT_l + (size_t)DQ * NPAD);        // 512*64
  unsigned short* wt_h   = (unsigned short*)(proj + (size_t)FD * DQ);   // 64*512
  unsigned short* wt_l   = wt_h + (size_t)DQ * FD;                      // 64*512

  init_kernel<<<NPAD / 64, 256, 0, stream>>>(user_emb, item_emb, out, egoT_h, egoT_l);

  for (int k = 0; k < N_LAYERS; ++k) {
    hipMemsetAsync(proj, 0, (size_t)FD * DQ * sizeof(float), stream);
    reduce_kernel<<<dim3(8, NPAD / (RED_CI * 64)), 256, 0, stream>>>(
        v, egoT_h, egoT_l, proj);
    prep_w<<<32, 256, 0, stream>>>(proj, filters + (size_t)k * FD, wt_h, wt_l);
    float scale = (k == N_LAYERS - 1) ? (1.0f / (N_LAYERS + 1)) : 1.0f;
    expand_kernel<<<(N_TOTAL + 127) / 128, 256, 0, stream>>>(
        v, wt_h, wt_l, out, egoT_h, egoT_l, scale, (k < N_LAYERS - 1) ? 1 : 0);
  }
}